// Round 15
// baseline (267.563 us; speedup 1.0000x reference)
//
#include <hip/hip_runtime.h>
#include <hip/hip_bf16.h>

#define NH 16
#define DH 64
#define LL 2048
#define DM 1024
#define SCALE2 0.1803368801111204f   /* 0.125 * log2(e) */
#define GUARD_HI 60.0f               /* overflow guard (~40 sigma) */

typedef __attribute__((ext_vector_type(4))) float f32x4;
typedef __attribute__((ext_vector_type(16))) float f32x16;
typedef __attribute__((ext_vector_type(8))) short bf16x8;

__device__ __forceinline__ unsigned pk2(float lo, float hi) {
    __hip_bfloat162 h = __float22bfloat162_rn(make_float2(lo, hi));
    union { __hip_bfloat162 h; unsigned u; } c; c.h = h; return c.u;
}
__device__ __forceinline__ bf16x8 cvt8(float4 a, float4 b) {
    union { bf16x8 v; unsigned u[4]; } r;
    r.u[0] = pk2(a.x, a.y); r.u[1] = pk2(a.z, a.w);
    r.u[2] = pk2(b.x, b.y); r.u[3] = pk2(b.z, b.w);
    return r.v;
}
__device__ __forceinline__ float exp2_fast(float x) {
    float y;
    asm("v_exp_f32 %0, %1" : "=v"(y) : "v"(x));
    return y;
}
__device__ __forceinline__ float keepf(float p, unsigned nw, int idx) {
    int k = (int)(nw << (31 - idx)) >> 31;
    unsigned pu = __builtin_bit_cast(unsigned, p) & (unsigned)k;
    return __builtin_bit_cast(float, pu);
}

// ---- mask pre-pack: per-q keep-words, bit j = !mask[b][q][kw*32+j] ----
__global__ __launch_bounds__(256) void pack_mask(const void* __restrict__ mask,
                                                 unsigned* __restrict__ bits)
{
    const int tid = threadIdx.x;
    const int lane = tid & 63;
    const int* mw = (const int*)mask;
    unsigned long long bad = __ballot((unsigned)mw[lane] > 1u);
    const bool is_int = (bad == 0ULL);

    const int wid = blockIdx.x * 256 + tid;
    const int kw = wid & 63;
    const int q64 = wid >> 6;
    unsigned m = 0;
    if (is_int) {
        const int* p = (const int*)mask + (size_t)q64 * LL + kw * 32;
        #pragma unroll
        for (int j = 0; j < 32; j += 4) {
            int4 v = *(const int4*)(p + j);
            m |= (v.x ? 1u : 0u) << j;
            m |= (v.y ? 1u : 0u) << (j + 1);
            m |= (v.z ? 1u : 0u) << (j + 2);
            m |= (v.w ? 1u : 0u) << (j + 3);
        }
    } else {
        const unsigned* p = (const unsigned*)((const unsigned char*)mask
                                              + (size_t)q64 * LL + kw * 32);
        #pragma unroll
        for (int j = 0; j < 8; ++j) {
            unsigned v = p[j];
            m |= (v & 1u) << (4 * j);
            m |= ((v >> 8) & 1u) << (4 * j + 1);
            m |= ((v >> 16) & 1u) << (4 * j + 2);
            m |= ((v >> 24) & 1u) << (4 * j + 3);
        }
    }
    bits[wid] = ~m;   // 1 = keep
}

// ---- merged K/V pre-convert into 32-key lane-linear tiles (2048 shorts each)
// K tile addr = d16*512 + hh*256 + key5*8 + i ; content K[key][16d16+8hh+i]
// V tile addr = m*1024 + dvhi*512 + hh*256 + dv5*8 + i ;
//   content V[16m + 4hh + (i&3)+8*(i>>2)][dv]
__global__ __launch_bounds__(256) void prep_kv(const float* __restrict__ K,
                                               const float* __restrict__ V,
                                               short* __restrict__ Kb,
                                               short* __restrict__ Vb)
{
    const int kt = blockIdx.x;            // 32-key tile 0..63
    const int h = blockIdx.y, b = blockIdx.z;
    const int tid = threadIdx.x;
    if (tid < 128) {
        const int key = tid >> 2;         // 0..31
        const int d16 = tid & 3;
        const float* src = K + ((size_t)b * LL + kt * 32 + key) * DM + h * DH + d16 * 16;
        float4 f0 = *(const float4*)(src);
        float4 f1 = *(const float4*)(src + 4);
        float4 f2 = *(const float4*)(src + 8);
        float4 f3 = *(const float4*)(src + 12);
        short* dst = Kb + (((size_t)(b * NH + h) * 64 + kt) << 11);
        const int base = d16 * 512 + key * 8;
        *(bf16x8*)&dst[base] = cvt8(f0, f1);        // hh=0
        *(bf16x8*)&dst[base + 256] = cvt8(f2, f3);  // hh=1
    } else {
        const int vt = tid - 128;
        const int kp = vt & 15;           // keys 2kp, 2kp+1 (0..31)
        const int dv8 = vt >> 4;          // 0..7
        const float* s0 = V + ((size_t)b * LL + kt * 32 + 2 * kp) * DM + h * DH + dv8 * 8;
        float4 a0 = *(const float4*)(s0);
        float4 a1 = *(const float4*)(s0 + 4);
        float4 b0 = *(const float4*)(s0 + DM);
        float4 b1 = *(const float4*)(s0 + DM + 4);
        float av[8] = {a0.x, a0.y, a0.z, a0.w, a1.x, a1.y, a1.z, a1.w};
        float bv[8] = {b0.x, b0.y, b0.z, b0.w, b1.x, b1.y, b1.z, b1.w};
        short* dst = Vb + (((size_t)(b * NH + h) * 64 + kt) << 11);
        const int key0 = 2 * kp;
        const int m = key0 >> 4;
        const int w16 = key0 & 15;
        const int hh = (w16 >> 2) & 1;
        const int i0 = (w16 & 3) + 4 * (w16 >> 3);
        #pragma unroll
        for (int j = 0; j < 8; ++j) {
            int dv = dv8 * 8 + j;
            int off = m * 1024 + (dv >> 5) * 512 + hh * 256 + (dv & 31) * 8 + i0;
            *(unsigned*)&dst[off] = pk2(av[j], bv[j]);
        }
    }
}

// ---- main v8: 2048 blocks (b,h,qblk,quarter) x 256 thr (4 waves x 32q);
//      512 keys/block, KVBLK=32, 16KB LDS -> 8 blocks/CU, 32 waves/CU ----
__global__ __launch_bounds__(256, 8) void mha_fwd8(
    const float* __restrict__ Q, const short* __restrict__ Kb,
    const short* __restrict__ Vb, const unsigned* __restrict__ mbits,
    float* __restrict__ out, _Float16* __restrict__ part,
    float* __restrict__ lm)
{
    const int bid = blockIdx.x;           // 2048 blocks
    const int xcd = bid & 7;
    const int j = bid >> 3;               // 0..255
    const int pair = xcd * 4 + (j >> 6);  // 0..31
    const int rem = j & 63;
    const int qblk = rem >> 2;            // 0..15
    const int quarter = rem & 3;          // kv quarter
    const int hd = pair & 15;
    const int b = pair >> 4;

    const int tid = threadIdx.x;
    const int wg = tid >> 6;              // wave 0..3
    const int lane = tid & 63;
    const int lq = lane & 31;             // q col
    const int hh = lane >> 5;
    const int qbase = qblk * 128 + wg * 32;

    __shared__ short smem[8192];          // 16 KB: K dbuf [0,4096) | V dbuf [4096,8192)

    const short* Ktile0 = Kb + ((size_t)(b * NH + hd) << 17) + ((size_t)(quarter * 16) << 11);
    const short* Vtile0 = Vb + ((size_t)(b * NH + hd) << 17) + ((size_t)(quarter * 16) << 11);
    const unsigned* Mrow = mbits + ((size_t)b * LL + qbase + lq) * 64 + quarter * 16;

    // prologue: mask(0) then tile 0
    unsigned mreg = Mrow[0];
    __builtin_amdgcn_global_load_lds(
        (const unsigned*)(Ktile0 + wg * 512 + lane * 8),
        (unsigned*)&smem[wg * 512], 16, 0, 0);
    __builtin_amdgcn_global_load_lds(
        (const unsigned*)(Vtile0 + wg * 512 + lane * 8),
        (unsigned*)&smem[4096 + wg * 512], 16, 0, 0);

    // Q fragments, pre-scaled: qf[d16] slot i = SCALE2*Q[q][16d16+8hh+i]
    bf16x8 qf[4];
    {
        const float* qp = Q + ((size_t)b * LL + qbase + lq) * DM + hd * DH + 8 * hh;
        #pragma unroll
        for (int d16 = 0; d16 < 4; ++d16) {
            float4 a = *(const float4*)(qp + 16 * d16);
            float4 c = *(const float4*)(qp + 16 * d16 + 4);
            a.x *= SCALE2; a.y *= SCALE2; a.z *= SCALE2; a.w *= SCALE2;
            c.x *= SCALE2; c.y *= SCALE2; c.z *= SCALE2; c.w *= SCALE2;
            qf[d16] = cvt8(a, c);
        }
    }

    f32x16 o0, o1;
    #pragma unroll
    for (int i = 0; i < 16; ++i) { o0[i] = 0.f; o1[i] = 0.f; }
    float l_own = 0.f;
    float m_shift = 0.f;
    const int sh4 = 4 * hh;

    #pragma unroll 2
    for (int t = 0; t < 16; ++t) {
        const int cur = t & 1;
        asm volatile("s_waitcnt vmcnt(0)" ::: "memory");
        __builtin_amdgcn_s_barrier();
        const unsigned mword = mreg;
        if (t + 1 < 16) {   // issue tile t+1 into the other buffer
            mreg = Mrow[t + 1];
            const short* kb_ = Ktile0 + (size_t)(t + 1) * 2048;
            const short* vb_ = Vtile0 + (size_t)(t + 1) * 2048;
            const int nb = (cur ^ 1) * 2048;
            __builtin_amdgcn_global_load_lds(
                (const unsigned*)(kb_ + wg * 512 + lane * 8),
                (unsigned*)&smem[nb + wg * 512], 16, 0, 0);
            __builtin_amdgcn_global_load_lds(
                (const unsigned*)(vb_ + wg * 512 + lane * 8),
                (unsigned*)&smem[4096 + nb + wg * 512], 16, 0, 0);
        }
        __builtin_amdgcn_sched_barrier(0);

        // ---- QK: 4 mfma_32x32x16 ----
        f32x16 s;
        #pragma unroll
        for (int i = 0; i < 16; ++i) s[i] = 0.f;
        __builtin_amdgcn_s_setprio(1);
        #pragma unroll
        for (int d16 = 0; d16 < 4; ++d16) {
            bf16x8 kf = *(const bf16x8*)&smem[cur * 2048 + d16 * 512 + lane * 8];
            s = __builtin_amdgcn_mfma_f32_32x32x16_bf16(kf, qf[d16], s, 0, 0, 0);
        }
        __builtin_amdgcn_s_setprio(0);

        // ---- overflow guard (never taken for sane data) ----
        {
            float a0 = fmaxf(fmaxf(s[0], s[1]), fmaxf(s[2], s[3]));
            float a1 = fmaxf(fmaxf(s[4], s[5]), fmaxf(s[6], s[7]));
            float a2 = fmaxf(fmaxf(s[8], s[9]), fmaxf(s[10], s[11]));
            float a3 = fmaxf(fmaxf(s[12], s[13]), fmaxf(s[14], s[15]));
            float mx = fmaxf(fmaxf(a0, a1), fmaxf(a2, a3));
            if (__builtin_expect(m_shift != 0.0f, 0)) {
                #pragma unroll
                for (int r = 0; r < 16; ++r) s[r] -= m_shift;
                mx -= m_shift;
            }
            if (!__all(mx <= GUARD_HI)) {
                float tmax = fmaxf(mx, __shfl_xor(mx, 32, 64));
                float shift = tmax - 30.0f;
                m_shift += shift;
                float alpha = exp2_fast(-shift);
                #pragma unroll
                for (int i = 0; i < 16; ++i) { o0[i] *= alpha; o1[i] *= alpha; }
                l_own *= alpha;
                #pragma unroll
                for (int r = 0; r < 16; ++r) s[r] -= shift;
            }
        }

        const unsigned nw = mword >> sh4;
        union { bf16x8 v; unsigned u[4]; } pa, pb;
        float lsum;
        {
            float p0 = keepf(exp2_fast(s[0]), nw, 0);
            float p1 = keepf(exp2_fast(s[1]), nw, 1);
            float p2 = keepf(exp2_fast(s[2]), nw, 2);
            float p3 = keepf(exp2_fast(s[3]), nw, 3);
            float p4 = keepf(exp2_fast(s[4]), nw, 8);
            float p5 = keepf(exp2_fast(s[5]), nw, 9);
            float p6 = keepf(exp2_fast(s[6]), nw, 10);
            float p7 = keepf(exp2_fast(s[7]), nw, 11);
            pa.u[0] = pk2(p0, p1); pa.u[1] = pk2(p2, p3);
            pa.u[2] = pk2(p4, p5); pa.u[3] = pk2(p6, p7);
            lsum = ((p0 + p1) + (p2 + p3)) + ((p4 + p5) + (p6 + p7));
        }
        {
            float p0 = keepf(exp2_fast(s[8]), nw, 16);
            float p1 = keepf(exp2_fast(s[9]), nw, 17);
            float p2 = keepf(exp2_fast(s[10]), nw, 18);
            float p3 = keepf(exp2_fast(s[11]), nw, 19);
            float p4 = keepf(exp2_fast(s[12]), nw, 24);
            float p5 = keepf(exp2_fast(s[13]), nw, 25);
            float p6 = keepf(exp2_fast(s[14]), nw, 26);
            float p7 = keepf(exp2_fast(s[15]), nw, 27);
            pb.u[0] = pk2(p0, p1); pb.u[1] = pk2(p2, p3);
            pb.u[2] = pk2(p4, p5); pb.u[3] = pk2(p6, p7);
            lsum += ((p0 + p1) + (p2 + p3)) + ((p4 + p5) + (p6 + p7));
        }
        l_own += lsum;

        // ---- PV: 4 mfma_32x32x16 (m=0 -> pa, m=1 -> pb) ----
        __builtin_amdgcn_s_setprio(1);
        {
            const int vb0 = 4096 + cur * 2048;
            bf16x8 v0 = *(const bf16x8*)&smem[vb0 + 0 * 1024 + 0 * 512 + lane * 8];
            bf16x8 v1 = *(const bf16x8*)&smem[vb0 + 0 * 1024 + 1 * 512 + lane * 8];
            o0 = __builtin_amdgcn_mfma_f32_32x32x16_bf16(v0, pa.v, o0, 0, 0, 0);
            o1 = __builtin_amdgcn_mfma_f32_32x32x16_bf16(v1, pa.v, o1, 0, 0, 0);
            bf16x8 v2 = *(const bf16x8*)&smem[vb0 + 1 * 1024 + 0 * 512 + lane * 8];
            bf16x8 v3 = *(const bf16x8*)&smem[vb0 + 1 * 1024 + 1 * 512 + lane * 8];
            o0 = __builtin_amdgcn_mfma_f32_32x32x16_bf16(v2, pb.v, o0, 0, 0, 0);
            o1 = __builtin_amdgcn_mfma_f32_32x32x16_bf16(v3, pb.v, o1, 0, 0, 0);
        }
        __builtin_amdgcn_s_setprio(0);
        // no end barrier: next iter's top barrier protects buffer reuse
    }

    // ---- epilogue: partials ----
    l_own += __shfl_xor(l_own, 32, 64);
    // fp16-range guard for split partials: fold 2^-32 into stored m
    if (__builtin_expect(l_own > 32768.f, 0)) {
        const float sc = 2.3283064365386963e-10f;  // 2^-32
        l_own *= sc;
        m_shift += 32.f;
        #pragma unroll
        for (int i = 0; i < 16; ++i) { o0[i] *= sc; o1[i] *= sc; }
    }
    if (quarter == 0) {   // split 0: fp32 partial directly into d_out
        float* fout = out + ((size_t)b * LL + qbase + lq) * DM + hd * DH + 4 * hh;
        #pragma unroll
        for (int rg = 0; rg < 4; ++rg) {
            float4 v0, v1;
            v0.x = o0[4 * rg + 0]; v0.y = o0[4 * rg + 1];
            v0.z = o0[4 * rg + 2]; v0.w = o0[4 * rg + 3];
            v1.x = o1[4 * rg + 0]; v1.y = o1[4 * rg + 1];
            v1.z = o1[4 * rg + 2]; v1.w = o1[4 * rg + 3];
            *(float4*)(fout + 8 * rg) = v0;
            *(float4*)(fout + 32 + 8 * rg) = v1;
        }
    } else {              // splits 1..3: fp16 partials in ws
        _Float16* po = part + ((size_t)(quarter - 1) * 2 + b) * ((size_t)LL * DM)
                     + (size_t)(qbase + lq) * DM + hd * DH + 4 * hh;
        union H4 { _Float16 h[4]; short4 s; };
        #pragma unroll
        for (int rg = 0; rg < 4; ++rg) {
            H4 u0, u1;
            #pragma unroll
            for (int jj = 0; jj < 4; ++jj) {
                u0.h[jj] = (_Float16)o0[4 * rg + jj];
                u1.h[jj] = (_Float16)o1[4 * rg + jj];
            }
            *(short4*)(po + 8 * rg) = u0.s;
            *(short4*)(po + 32 + 8 * rg) = u1.s;
        }
    }
    if (hh == 0) {
        size_t li = ((((size_t)quarter * 2 + b) * NH + hd) * LL + (qbase + lq)) * 2;
        lm[li] = l_own;
        lm[li + 1] = m_shift;
    }
}

// ---- combine 4 splits: out = sum_s o_s*a_s / sum_s l_s*a_s ----
__global__ __launch_bounds__(256) void combine4(const _Float16* __restrict__ part,
                                                const float* __restrict__ lm,
                                                float* __restrict__ out)
{
    const size_t idx = (size_t)blockIdx.x * 256 + threadIdx.x;
    const size_t flat = idx * 4;
    const int b = (int)(flat >> 21);
    const int r = (int)(flat & 2097151);
    const int q = r >> 10;
    const int col = r & 1023;
    const int hd = col >> 6;

    float l[4], m[4];
    #pragma unroll
    for (int s = 0; s < 4; ++s) {
        size_t li = ((((size_t)s * 2 + b) * NH + hd) * LL + q) * 2;
        l[s] = lm[li];
        m[s] = lm[li + 1];
    }
    float M = fmaxf(fmaxf(m[0], m[1]), fmaxf(m[2], m[3]));
    float a[4];
    #pragma unroll
    for (int s = 0; s < 4; ++s) a[s] = exp2_fast(m[s] - M);
    float denom = l[0] * a[0] + l[1] * a[1] + l[2] * a[2] + l[3] * a[3];
    float inv = __builtin_amdgcn_rcpf(denom);

    float4 acc = *(const float4*)(out + flat);   // split-0 fp32 partial
    acc.x *= a[0]; acc.y *= a[0]; acc.z *= a[0]; acc.w *= a[0];
    #pragma unroll
    for (int s = 1; s < 4; ++s) {
        const _Float16* ph = part + ((size_t)(s - 1) * 2 + b) * ((size_t)LL * DM)
                           + (size_t)q * DM + col;
        union H4 { short4 s4; _Float16 h[4]; } u;
        u.s4 = *(const short4*)(ph);
        acc.x += (float)u.h[0] * a[s];
        acc.y += (float)u.h[1] * a[s];
        acc.z += (float)u.h[2] * a[s];
        acc.w += (float)u.h[3] * a[s];
    }
    acc.x *= inv; acc.y *= inv; acc.z *= inv; acc.w *= inv;
    *(float4*)(out + flat) = acc;
}

extern "C" void kernel_launch(void* const* d_in, const int* in_sizes, int n_in,
                              void* d_out, int out_size, void* d_ws, size_t ws_size,
                              hipStream_t stream) {
    const float* Q = (const float*)d_in[0];
    const float* K = (const float*)d_in[1];
    const float* V = (const float*)d_in[2];
    const void* mask = d_in[3];
    float* out = (float*)d_out;

    const size_t MASK_B = (size_t)2 * LL * 64 * 4;          // 1 MB
    const size_t K_B = (size_t)2 * NH * 64 * 2048 * 2;      // 8 MB
    const size_t V_B = K_B;                                 // 8 MB
    const size_t PART_B = (size_t)3 * 2 * LL * DM * 2;      // 24 MB (fp16, splits 1-3)
    const size_t LM_B = (size_t)4 * 2 * NH * LL * 2 * 4;    // 2 MB

    unsigned* bits = (unsigned*)d_ws;
    short* Kb = (short*)((char*)d_ws + MASK_B);
    short* Vb = (short*)((char*)d_ws + MASK_B + K_B);
    _Float16* part = (_Float16*)((char*)d_ws + MASK_B + K_B + V_B);
    float* lm = (float*)((char*)d_ws + MASK_B + K_B + V_B + PART_B);

    pack_mask<<<dim3(2 * LL * 64 / 256), dim3(256), 0, stream>>>(mask, bits);
    prep_kv<<<dim3(64, NH, 2), dim3(256), 0, stream>>>(K, V, Kb, Vb);
    mha_fwd8<<<dim3(2048), dim3(256), 0, stream>>>(Q, Kb, Vb, bits, out, part, lm);
    combine4<<<dim3(4096), dim3(256), 0, stream>>>(part, lm, out);
}

// Round 16
// 96.616 us; speedup vs baseline: 2.7694x; 2.7694x over previous
//
#include <hip/hip_runtime.h>
#include <hip/hip_bf16.h>

#define NH 16
#define DH 64
#define LL 2048
#define DM 1024
#define SCALE2 0.1803368801111204f   /* 0.125 * log2(e) */
#define GUARD_HI 60.0f               /* overflow guard (~40 sigma) */

typedef __attribute__((ext_vector_type(4))) float f32x4;
typedef __attribute__((ext_vector_type(16))) float f32x16;
typedef __attribute__((ext_vector_type(8))) short bf16x8;

__device__ __forceinline__ unsigned pk2(float lo, float hi) {
    __hip_bfloat162 h = __float22bfloat162_rn(make_float2(lo, hi));
    union { __hip_bfloat162 h; unsigned u; } c; c.h = h; return c.u;
}
__device__ __forceinline__ bf16x8 cvt8(float4 a, float4 b) {
    union { bf16x8 v; unsigned u[4]; } r;
    r.u[0] = pk2(a.x, a.y); r.u[1] = pk2(a.z, a.w);
    r.u[2] = pk2(b.x, b.y); r.u[3] = pk2(b.z, b.w);
    return r.v;
}
__device__ __forceinline__ float exp2_fast(float x) {
    float y;
    asm("v_exp_f32 %0, %1" : "=v"(y) : "v"(x));
    return y;
}
__device__ __forceinline__ float keepf(float p, unsigned nw, int idx) {
    int k = (int)(nw << (31 - idx)) >> 31;
    unsigned pu = __builtin_bit_cast(unsigned, p) & (unsigned)k;
    return __builtin_bit_cast(float, pu);
}

// ---- mask pre-pack: per-q keep-words, bit j = !mask[b][q][kw*32+j] ----
__global__ __launch_bounds__(256) void pack_mask(const void* __restrict__ mask,
                                                 unsigned* __restrict__ bits)
{
    const int tid = threadIdx.x;
    const int lane = tid & 63;
    const int* mw = (const int*)mask;
    unsigned long long bad = __ballot((unsigned)mw[lane] > 1u);
    const bool is_int = (bad == 0ULL);

    const int wid = blockIdx.x * 256 + tid;
    const int kw = wid & 63;
    const int q64 = wid >> 6;
    unsigned m = 0;
    if (is_int) {
        const int* p = (const int*)mask + (size_t)q64 * LL + kw * 32;
        #pragma unroll
        for (int j = 0; j < 32; j += 4) {
            int4 v = *(const int4*)(p + j);
            m |= (v.x ? 1u : 0u) << j;
            m |= (v.y ? 1u : 0u) << (j + 1);
            m |= (v.z ? 1u : 0u) << (j + 2);
            m |= (v.w ? 1u : 0u) << (j + 3);
        }
    } else {
        const unsigned* p = (const unsigned*)((const unsigned char*)mask
                                              + (size_t)q64 * LL + kw * 32);
        #pragma unroll
        for (int j = 0; j < 8; ++j) {
            unsigned v = p[j];
            m |= (v & 1u) << (4 * j);
            m |= ((v >> 8) & 1u) << (4 * j + 1);
            m |= ((v >> 16) & 1u) << (4 * j + 2);
            m |= ((v >> 24) & 1u) << (4 * j + 3);
        }
    }
    bits[wid] = ~m;   // 1 = keep
}

// ---- merged K/V pre-convert into 32-key lane-linear tiles (2048 shorts each)
// K tile addr = d16*512 + hh*256 + key5*8 + i ; content K[key][16d16+8hh+i]
// V tile addr = m*1024 + dvhi*512 + hh*256 + dv5*8 + i ;
//   content V[16m + 4hh + (i&3)+8*(i>>2)][dv]
__global__ __launch_bounds__(256) void prep_kv(const float* __restrict__ K,
                                               const float* __restrict__ V,
                                               short* __restrict__ Kb,
                                               short* __restrict__ Vb)
{
    const int kt = blockIdx.x;            // 32-key tile 0..63
    const int h = blockIdx.y, b = blockIdx.z;
    const int tid = threadIdx.x;
    if (tid < 128) {
        const int key = tid >> 2;         // 0..31
        const int d16 = tid & 3;
        const float* src = K + ((size_t)b * LL + kt * 32 + key) * DM + h * DH + d16 * 16;
        float4 f0 = *(const float4*)(src);
        float4 f1 = *(const float4*)(src + 4);
        float4 f2 = *(const float4*)(src + 8);
        float4 f3 = *(const float4*)(src + 12);
        short* dst = Kb + (((size_t)(b * NH + h) * 64 + kt) << 11);
        const int base = d16 * 512 + key * 8;
        *(bf16x8*)&dst[base] = cvt8(f0, f1);        // hh=0
        *(bf16x8*)&dst[base + 256] = cvt8(f2, f3);  // hh=1
    } else {
        const int vt = tid - 128;
        const int kp = vt & 15;           // keys 2kp, 2kp+1 (0..31)
        const int dv8 = vt >> 4;          // 0..7
        const float* s0 = V + ((size_t)b * LL + kt * 32 + 2 * kp) * DM + h * DH + dv8 * 8;
        float4 a0 = *(const float4*)(s0);
        float4 a1 = *(const float4*)(s0 + 4);
        float4 b0 = *(const float4*)(s0 + DM);
        float4 b1 = *(const float4*)(s0 + DM + 4);
        float av[8] = {a0.x, a0.y, a0.z, a0.w, a1.x, a1.y, a1.z, a1.w};
        float bv[8] = {b0.x, b0.y, b0.z, b0.w, b1.x, b1.y, b1.z, b1.w};
        short* dst = Vb + (((size_t)(b * NH + h) * 64 + kt) << 11);
        const int key0 = 2 * kp;
        const int m = key0 >> 4;
        const int w16 = key0 & 15;
        const int hh = (w16 >> 2) & 1;
        const int i0 = (w16 & 3) + 4 * (w16 >> 3);
        #pragma unroll
        for (int j = 0; j < 8; ++j) {
            int dv = dv8 * 8 + j;
            int off = m * 1024 + (dv >> 5) * 512 + hh * 256 + (dv & 31) * 8 + i0;
            *(unsigned*)&dst[off] = pk2(av[j], bv[j]);
        }
    }
}

// ---- main v8b: 2048 blocks (b,h,qblk,quarter) x 256 thr (4 waves x 32q);
//      512 keys/block, KVBLK=32, 16KB LDS. launch_bounds(256,4): allocator
//      lands ~60 VGPR (R14-measured) -> HW co-schedules 8 blocks/CU ----
__global__ __launch_bounds__(256, 4) void mha_fwd8(
    const float* __restrict__ Q, const short* __restrict__ Kb,
    const short* __restrict__ Vb, const unsigned* __restrict__ mbits,
    float* __restrict__ out, _Float16* __restrict__ part,
    float* __restrict__ lm)
{
    const int bid = blockIdx.x;           // 2048 blocks
    const int xcd = bid & 7;
    const int j = bid >> 3;               // 0..255
    const int pair = xcd * 4 + (j >> 6);  // 0..31
    const int rem = j & 63;
    const int qblk = rem >> 2;            // 0..15
    const int quarter = rem & 3;          // kv quarter
    const int hd = pair & 15;
    const int b = pair >> 4;

    const int tid = threadIdx.x;
    const int wg = tid >> 6;              // wave 0..3
    const int lane = tid & 63;
    const int lq = lane & 31;             // q col
    const int hh = lane >> 5;
    const int qbase = qblk * 128 + wg * 32;

    __shared__ short smem[8192];          // 16 KB: K dbuf [0,4096) | V dbuf [4096,8192)

    const short* Ktile0 = Kb + ((size_t)(b * NH + hd) << 17) + ((size_t)(quarter * 16) << 11);
    const short* Vtile0 = Vb + ((size_t)(b * NH + hd) << 17) + ((size_t)(quarter * 16) << 11);
    const unsigned* Mrow = mbits + ((size_t)b * LL + qbase + lq) * 64 + quarter * 16;

    // prologue: mask(0) then tile 0
    unsigned mreg = Mrow[0];
    __builtin_amdgcn_global_load_lds(
        (const unsigned*)(Ktile0 + wg * 512 + lane * 8),
        (unsigned*)&smem[wg * 512], 16, 0, 0);
    __builtin_amdgcn_global_load_lds(
        (const unsigned*)(Vtile0 + wg * 512 + lane * 8),
        (unsigned*)&smem[4096 + wg * 512], 16, 0, 0);

    // Q fragments, pre-scaled: qf[d16] slot i = SCALE2*Q[q][16d16+8hh+i]
    bf16x8 qf[4];
    {
        const float* qp = Q + ((size_t)b * LL + qbase + lq) * DM + hd * DH + 8 * hh;
        #pragma unroll
        for (int d16 = 0; d16 < 4; ++d16) {
            float4 a = *(const float4*)(qp + 16 * d16);
            float4 c = *(const float4*)(qp + 16 * d16 + 4);
            a.x *= SCALE2; a.y *= SCALE2; a.z *= SCALE2; a.w *= SCALE2;
            c.x *= SCALE2; c.y *= SCALE2; c.z *= SCALE2; c.w *= SCALE2;
            qf[d16] = cvt8(a, c);
        }
    }

    f32x16 o0, o1;
    #pragma unroll
    for (int i = 0; i < 16; ++i) { o0[i] = 0.f; o1[i] = 0.f; }
    float l_own = 0.f;
    float m_shift = 0.f;
    const int sh4 = 4 * hh;

    #pragma unroll 2
    for (int t = 0; t < 16; ++t) {
        const int cur = t & 1;
        asm volatile("s_waitcnt vmcnt(0)" ::: "memory");
        __builtin_amdgcn_s_barrier();
        const unsigned mword = mreg;
        if (t + 1 < 16) {   // issue tile t+1 into the other buffer
            mreg = Mrow[t + 1];
            const short* kb_ = Ktile0 + (size_t)(t + 1) * 2048;
            const short* vb_ = Vtile0 + (size_t)(t + 1) * 2048;
            const int nb = (cur ^ 1) * 2048;
            __builtin_amdgcn_global_load_lds(
                (const unsigned*)(kb_ + wg * 512 + lane * 8),
                (unsigned*)&smem[nb + wg * 512], 16, 0, 0);
            __builtin_amdgcn_global_load_lds(
                (const unsigned*)(vb_ + wg * 512 + lane * 8),
                (unsigned*)&smem[4096 + nb + wg * 512], 16, 0, 0);
        }
        __builtin_amdgcn_sched_barrier(0);

        // ---- QK: 4 mfma_32x32x16 ----
        f32x16 s;
        #pragma unroll
        for (int i = 0; i < 16; ++i) s[i] = 0.f;
        __builtin_amdgcn_s_setprio(1);
        #pragma unroll
        for (int d16 = 0; d16 < 4; ++d16) {
            bf16x8 kf = *(const bf16x8*)&smem[cur * 2048 + d16 * 512 + lane * 8];
            s = __builtin_amdgcn_mfma_f32_32x32x16_bf16(kf, qf[d16], s, 0, 0, 0);
        }
        __builtin_amdgcn_s_setprio(0);

        // ---- overflow guard (never taken for sane data) ----
        {
            float a0 = fmaxf(fmaxf(s[0], s[1]), fmaxf(s[2], s[3]));
            float a1 = fmaxf(fmaxf(s[4], s[5]), fmaxf(s[6], s[7]));
            float a2 = fmaxf(fmaxf(s[8], s[9]), fmaxf(s[10], s[11]));
            float a3 = fmaxf(fmaxf(s[12], s[13]), fmaxf(s[14], s[15]));
            float mx = fmaxf(fmaxf(a0, a1), fmaxf(a2, a3));
            if (__builtin_expect(m_shift != 0.0f, 0)) {
                #pragma unroll
                for (int r = 0; r < 16; ++r) s[r] -= m_shift;
                mx -= m_shift;
            }
            if (!__all(mx <= GUARD_HI)) {
                float tmax = fmaxf(mx, __shfl_xor(mx, 32, 64));
                float shift = tmax - 30.0f;
                m_shift += shift;
                float alpha = exp2_fast(-shift);
                #pragma unroll
                for (int i = 0; i < 16; ++i) { o0[i] *= alpha; o1[i] *= alpha; }
                l_own *= alpha;
                #pragma unroll
                for (int r = 0; r < 16; ++r) s[r] -= shift;
            }
        }

        const unsigned nw = mword >> sh4;
        union { bf16x8 v; unsigned u[4]; } pa, pb;
        float lsum;
        {
            float p0 = keepf(exp2_fast(s[0]), nw, 0);
            float p1 = keepf(exp2_fast(s[1]), nw, 1);
            float p2 = keepf(exp2_fast(s[2]), nw, 2);
            float p3 = keepf(exp2_fast(s[3]), nw, 3);
            float p4 = keepf(exp2_fast(s[4]), nw, 8);
            float p5 = keepf(exp2_fast(s[5]), nw, 9);
            float p6 = keepf(exp2_fast(s[6]), nw, 10);
            float p7 = keepf(exp2_fast(s[7]), nw, 11);
            pa.u[0] = pk2(p0, p1); pa.u[1] = pk2(p2, p3);
            pa.u[2] = pk2(p4, p5); pa.u[3] = pk2(p6, p7);
            lsum = ((p0 + p1) + (p2 + p3)) + ((p4 + p5) + (p6 + p7));
        }
        {
            float p0 = keepf(exp2_fast(s[8]), nw, 16);
            float p1 = keepf(exp2_fast(s[9]), nw, 17);
            float p2 = keepf(exp2_fast(s[10]), nw, 18);
            float p3 = keepf(exp2_fast(s[11]), nw, 19);
            float p4 = keepf(exp2_fast(s[12]), nw, 24);
            float p5 = keepf(exp2_fast(s[13]), nw, 25);
            float p6 = keepf(exp2_fast(s[14]), nw, 26);
            float p7 = keepf(exp2_fast(s[15]), nw, 27);
            pb.u[0] = pk2(p0, p1); pb.u[1] = pk2(p2, p3);
            pb.u[2] = pk2(p4, p5); pb.u[3] = pk2(p6, p7);
            lsum += ((p0 + p1) + (p2 + p3)) + ((p4 + p5) + (p6 + p7));
        }
        l_own += lsum;

        // ---- PV: 4 mfma_32x32x16 (m=0 -> pa, m=1 -> pb) ----
        __builtin_amdgcn_s_setprio(1);
        {
            const int vb0 = 4096 + cur * 2048;
            bf16x8 v0 = *(const bf16x8*)&smem[vb0 + 0 * 1024 + 0 * 512 + lane * 8];
            bf16x8 v1 = *(const bf16x8*)&smem[vb0 + 0 * 1024 + 1 * 512 + lane * 8];
            o0 = __builtin_amdgcn_mfma_f32_32x32x16_bf16(v0, pa.v, o0, 0, 0, 0);
            o1 = __builtin_amdgcn_mfma_f32_32x32x16_bf16(v1, pa.v, o1, 0, 0, 0);
            bf16x8 v2 = *(const bf16x8*)&smem[vb0 + 1 * 1024 + 0 * 512 + lane * 8];
            bf16x8 v3 = *(const bf16x8*)&smem[vb0 + 1 * 1024 + 1 * 512 + lane * 8];
            o0 = __builtin_amdgcn_mfma_f32_32x32x16_bf16(v2, pb.v, o0, 0, 0, 0);
            o1 = __builtin_amdgcn_mfma_f32_32x32x16_bf16(v3, pb.v, o1, 0, 0, 0);
        }
        __builtin_amdgcn_s_setprio(0);
        // no end barrier: next iter's top barrier protects buffer reuse
    }

    // ---- epilogue: partials ----
    l_own += __shfl_xor(l_own, 32, 64);
    // fp16-range guard for split partials: fold 2^-32 into stored m
    if (__builtin_expect(l_own > 32768.f, 0)) {
        const float sc = 2.3283064365386963e-10f;  // 2^-32
        l_own *= sc;
        m_shift += 32.f;
        #pragma unroll
        for (int i = 0; i < 16; ++i) { o0[i] *= sc; o1[i] *= sc; }
    }
    if (quarter == 0) {   // split 0: fp32 partial directly into d_out
        float* fout = out + ((size_t)b * LL + qbase + lq) * DM + hd * DH + 4 * hh;
        #pragma unroll
        for (int rg = 0; rg < 4; ++rg) {
            float4 v0, v1;
            v0.x = o0[4 * rg + 0]; v0.y = o0[4 * rg + 1];
            v0.z = o0[4 * rg + 2]; v0.w = o0[4 * rg + 3];
            v1.x = o1[4 * rg + 0]; v1.y = o1[4 * rg + 1];
            v1.z = o1[4 * rg + 2]; v1.w = o1[4 * rg + 3];
            *(float4*)(fout + 8 * rg) = v0;
            *(float4*)(fout + 32 + 8 * rg) = v1;
        }
    } else {              // splits 1..3: fp16 partials in ws
        _Float16* po = part + ((size_t)(quarter - 1) * 2 + b) * ((size_t)LL * DM)
                     + (size_t)(qbase + lq) * DM + hd * DH + 4 * hh;
        union H4 { _Float16 h[4]; short4 s; };
        #pragma unroll
        for (int rg = 0; rg < 4; ++rg) {
            H4 u0, u1;
            #pragma unroll
            for (int jj = 0; jj < 4; ++jj) {
                u0.h[jj] = (_Float16)o0[4 * rg + jj];
                u1.h[jj] = (_Float16)o1[4 * rg + jj];
            }
            *(short4*)(po + 8 * rg) = u0.s;
            *(short4*)(po + 32 + 8 * rg) = u1.s;
        }
    }
    if (hh == 0) {
        size_t li = ((((size_t)quarter * 2 + b) * NH + hd) * LL + (qbase + lq)) * 2;
        lm[li] = l_own;
        lm[li + 1] = m_shift;
    }
}

// ---- combine 4 splits: out = sum_s o_s*a_s / sum_s l_s*a_s ----
__global__ __launch_bounds__(256) void combine4(const _Float16* __restrict__ part,
                                                const float* __restrict__ lm,
                                                float* __restrict__ out)
{
    const size_t idx = (size_t)blockIdx.x * 256 + threadIdx.x;
    const size_t flat = idx * 4;
    const int b = (int)(flat >> 21);
    const int r = (int)(flat & 2097151);
    const int q = r >> 10;
    const int col = r & 1023;
    const int hd = col >> 6;

    float l[4], m[4];
    #pragma unroll
    for (int s = 0; s < 4; ++s) {
        size_t li = ((((size_t)s * 2 + b) * NH + hd) * LL + q) * 2;
        l[s] = lm[li];
        m[s] = lm[li + 1];
    }
    float M = fmaxf(fmaxf(m[0], m[1]), fmaxf(m[2], m[3]));
    float a[4];
    #pragma unroll
    for (int s = 0; s < 4; ++s) a[s] = exp2_fast(m[s] - M);
    float denom = l[0] * a[0] + l[1] * a[1] + l[2] * a[2] + l[3] * a[3];
    float inv = __builtin_amdgcn_rcpf(denom);

    float4 acc = *(const float4*)(out + flat);   // split-0 fp32 partial
    acc.x *= a[0]; acc.y *= a[0]; acc.z *= a[0]; acc.w *= a[0];
    #pragma unroll
    for (int s = 1; s < 4; ++s) {
        const _Float16* ph = part + ((size_t)(s - 1) * 2 + b) * ((size_t)LL * DM)
                           + (size_t)q * DM + col;
        union H4 { short4 s4; _Float16 h[4]; } u;
        u.s4 = *(const short4*)(ph);
        acc.x += (float)u.h[0] * a[s];
        acc.y += (float)u.h[1] * a[s];
        acc.z += (float)u.h[2] * a[s];
        acc.w += (float)u.h[3] * a[s];
    }
    acc.x *= inv; acc.y *= inv; acc.z *= inv; acc.w *= inv;
    *(float4*)(out + flat) = acc;
}

extern "C" void kernel_launch(void* const* d_in, const int* in_sizes, int n_in,
                              void* d_out, int out_size, void* d_ws, size_t ws_size,
                              hipStream_t stream) {
    const float* Q = (const float*)d_in[0];
    const float* K = (const float*)d_in[1];
    const float* V = (const float*)d_in[2];
    const void* mask = d_in[3];
    float* out = (float*)d_out;

    const size_t MASK_B = (size_t)2 * LL * 64 * 4;          // 1 MB
    const size_t K_B = (size_t)2 * NH * 64 * 2048 * 2;      // 8 MB
    const size_t V_B = K_B;                                 // 8 MB
    const size_t PART_B = (size_t)3 * 2 * LL * DM * 2;      // 24 MB (fp16, splits 1-3)
    const size_t LM_B = (size_t)4 * 2 * NH * LL * 2 * 4;    // 2 MB

    unsigned* bits = (unsigned*)d_ws;
    short* Kb = (short*)((char*)d_ws + MASK_B);
    short* Vb = (short*)((char*)d_ws + MASK_B + K_B);
    _Float16* part = (_Float16*)((char*)d_ws + MASK_B + K_B + V_B);
    float* lm = (float*)((char*)d_ws + MASK_B + K_B + V_B + PART_B);

    pack_mask<<<dim3(2 * LL * 64 / 256), dim3(256), 0, stream>>>(mask, bits);
    prep_kv<<<dim3(64, NH, 2), dim3(256), 0, stream>>>(K, V, Kb, Vb);
    mha_fwd8<<<dim3(2048), dim3(256), 0, stream>>>(Q, Kb, Vb, bits, out, part, lm);
    combine4<<<dim3(4096), dim3(256), 0, stream>>>(part, lm, out);
}

// Round 17
// 76.950 us; speedup vs baseline: 3.4771x; 1.2556x over previous
//
#include <hip/hip_runtime.h>
#include <hip/hip_bf16.h>

#define NH 16
#define DH 64
#define LL 2048
#define DM 1024
#define SCALE2 0.1803368801111204f   /* 0.125 * log2(e) */

typedef __attribute__((ext_vector_type(4))) float f32x4;
typedef __attribute__((ext_vector_type(16))) float f32x16;
typedef __attribute__((ext_vector_type(8))) short bf16x8;

__device__ __forceinline__ unsigned pk2(float lo, float hi) {
    __hip_bfloat162 h = __float22bfloat162_rn(make_float2(lo, hi));
    union { __hip_bfloat162 h; unsigned u; } c; c.h = h; return c.u;
}
__device__ __forceinline__ bf16x8 cvt8(float4 a, float4 b) {
    union { bf16x8 v; unsigned u[4]; } r;
    r.u[0] = pk2(a.x, a.y); r.u[1] = pk2(a.z, a.w);
    r.u[2] = pk2(b.x, b.y); r.u[3] = pk2(b.z, b.w);
    return r.v;
}
__device__ __forceinline__ float exp2_fast(float x) {
    float y;
    asm("v_exp_f32 %0, %1" : "=v"(y) : "v"(x));
    return y;
}
__device__ __forceinline__ float keepf(float p, unsigned nw, int idx) {
    int k = (int)(nw << (31 - idx)) >> 31;
    unsigned pu = __builtin_bit_cast(unsigned, p) & (unsigned)k;
    return __builtin_bit_cast(float, pu);
}

// exp + mask + pack for one 32-key score block (bit map: keys 8*(r>>2)+(r&3))
struct PP { bf16x8 pa, pb; float lsum; };
__device__ __forceinline__ PP packP(const f32x16& s, unsigned nw) {
    PP r;
    union { bf16x8 v; unsigned u[4]; } pa, pb;
    float p0 = keepf(exp2_fast(s[0]), nw, 0);
    float p1 = keepf(exp2_fast(s[1]), nw, 1);
    float p2 = keepf(exp2_fast(s[2]), nw, 2);
    float p3 = keepf(exp2_fast(s[3]), nw, 3);
    float p4 = keepf(exp2_fast(s[4]), nw, 8);
    float p5 = keepf(exp2_fast(s[5]), nw, 9);
    float p6 = keepf(exp2_fast(s[6]), nw, 10);
    float p7 = keepf(exp2_fast(s[7]), nw, 11);
    pa.u[0] = pk2(p0, p1); pa.u[1] = pk2(p2, p3);
    pa.u[2] = pk2(p4, p5); pa.u[3] = pk2(p6, p7);
    float lsum = ((p0 + p1) + (p2 + p3)) + ((p4 + p5) + (p6 + p7));
    float q0 = keepf(exp2_fast(s[8]), nw, 16);
    float q1 = keepf(exp2_fast(s[9]), nw, 17);
    float q2 = keepf(exp2_fast(s[10]), nw, 18);
    float q3 = keepf(exp2_fast(s[11]), nw, 19);
    float q4 = keepf(exp2_fast(s[12]), nw, 24);
    float q5 = keepf(exp2_fast(s[13]), nw, 25);
    float q6 = keepf(exp2_fast(s[14]), nw, 26);
    float q7 = keepf(exp2_fast(s[15]), nw, 27);
    pb.u[0] = pk2(q0, q1); pb.u[1] = pk2(q2, q3);
    pb.u[2] = pk2(q4, q5); pb.u[3] = pk2(q6, q7);
    lsum += ((q0 + q1) + (q2 + q3)) + ((q4 + q5) + (q6 + q7));
    r.pa = pa.v; r.pb = pb.v; r.lsum = lsum;
    return r;
}

// ---- mask pre-pack: per-q keep-words, bit j = !mask[b][q][kw*32+j] ----
__global__ __launch_bounds__(256) void pack_mask(const void* __restrict__ mask,
                                                 unsigned* __restrict__ bits)
{
    const int tid = threadIdx.x;
    const int lane = tid & 63;
    const int* mw = (const int*)mask;
    unsigned long long bad = __ballot((unsigned)mw[lane] > 1u);
    const bool is_int = (bad == 0ULL);

    const int wid = blockIdx.x * 256 + tid;
    const int kw = wid & 63;
    const int q64 = wid >> 6;
    unsigned m = 0;
    if (is_int) {
        const int* p = (const int*)mask + (size_t)q64 * LL + kw * 32;
        #pragma unroll
        for (int j = 0; j < 32; j += 4) {
            int4 v = *(const int4*)(p + j);
            m |= (v.x ? 1u : 0u) << j;
            m |= (v.y ? 1u : 0u) << (j + 1);
            m |= (v.z ? 1u : 0u) << (j + 2);
            m |= (v.w ? 1u : 0u) << (j + 3);
        }
    } else {
        const unsigned* p = (const unsigned*)((const unsigned char*)mask
                                              + (size_t)q64 * LL + kw * 32);
        #pragma unroll
        for (int j = 0; j < 8; ++j) {
            unsigned v = p[j];
            m |= (v & 1u) << (4 * j);
            m |= ((v >> 8) & 1u) << (4 * j + 1);
            m |= ((v >> 16) & 1u) << (4 * j + 2);
            m |= ((v >> 24) & 1u) << (4 * j + 3);
        }
    }
    bits[wid] = ~m;   // 1 = keep
}

// ---- merged K/V pre-convert: 64-key lane-linear tiles (4096 shorts each) ----
// K: addr = d16*1024 + (key>>5)*512 + hh*256 + (key&31)*8 + i
//    content K[key][16*d16 + 8*hh + i]
// V: addr = m*1024 + (dv>>5)*512 + hh*256 + (dv&31)*8 + i
//    content V[16m + 4hh + (i&3) + 8*(i>>2)][dv]
__global__ __launch_bounds__(512) void prep_kv(const float* __restrict__ K,
                                               const float* __restrict__ V,
                                               short* __restrict__ Kb,
                                               short* __restrict__ Vb)
{
    const int kt = blockIdx.x, h = blockIdx.y, b = blockIdx.z;
    const int tid = threadIdx.x;
    if (tid < 256) {
        const int key = tid >> 2;
        const int d16 = tid & 3;
        const float* src = K + ((size_t)b * LL + kt * 64 + key) * DM + h * DH + d16 * 16;
        float4 f0 = *(const float4*)(src);
        float4 f1 = *(const float4*)(src + 4);
        float4 f2 = *(const float4*)(src + 8);
        float4 f3 = *(const float4*)(src + 12);
        short* dst = Kb + (((size_t)(b * NH + h) * 32 + kt) << 12);
        const int base = d16 * 1024 + (key >> 5) * 512 + (key & 31) * 8;
        *(bf16x8*)&dst[base] = cvt8(f0, f1);           // hh=0
        *(bf16x8*)&dst[base + 256] = cvt8(f2, f3);     // hh=1
    } else {
        const int vt = tid - 256;
        const int kp = vt & 31;               // keys 2kp, 2kp+1
        const int dv8 = vt >> 5;
        const float* s0 = V + ((size_t)b * LL + kt * 64 + 2 * kp) * DM + h * DH + dv8 * 8;
        float4 a0 = *(const float4*)(s0);
        float4 a1 = *(const float4*)(s0 + 4);
        float4 b0 = *(const float4*)(s0 + DM);
        float4 b1 = *(const float4*)(s0 + DM + 4);
        float av[8] = {a0.x, a0.y, a0.z, a0.w, a1.x, a1.y, a1.z, a1.w};
        float bv[8] = {b0.x, b0.y, b0.z, b0.w, b1.x, b1.y, b1.z, b1.w};
        short* dst = Vb + (((size_t)(b * NH + h) * 32 + kt) << 12);
        const int key0 = 2 * kp;
        const int m = key0 >> 4;
        const int w16 = key0 & 15;
        const int hh = (w16 >> 2) & 1;
        const int i0 = (w16 & 3) + 4 * (w16 >> 3);
        #pragma unroll
        for (int j = 0; j < 8; ++j) {
            int dv = dv8 * 8 + j;
            int off = m * 1024 + (dv >> 5) * 512 + hh * 256 + (dv & 31) * 8 + i0;
            *(unsigned*)&dst[off] = pk2(av[j], bv[j]);
        }
    }
}

// ---- main (R13 structure, lsum-guard): 512 blocks x 512 thr,
//      2 kv-groups x 4 waves x 32q, 64-key tiles, counted vmcnt(5) ----
__global__ __launch_bounds__(512, 4) void mha_fwd6(
    const float* __restrict__ Q, const short* __restrict__ Kb,
    const short* __restrict__ Vb, const unsigned* __restrict__ mbits,
    float* __restrict__ out)
{
    const int bid = blockIdx.x;
    const int xcd = bid & 7;
    const int j = bid >> 3;
    const int pair = xcd * 4 + (j >> 4);
    const int qblk = j & 15;
    const int hd = pair & 15;
    const int b = pair >> 4;

    const int tid = threadIdx.x;
    const int w = tid >> 6;
    const int g = w >> 2;                 // kv-group 0/1
    const int wg = w & 3;                 // wave in group
    const int lane = tid & 63;
    const int lq = lane & 31;
    const int hh = lane >> 5;
    const int qbase = qblk * 128 + wg * 32;

    __shared__ short smem[32768];         // 64 KB
    #define KOFF(gg, cc) (((gg) * 2 + (cc)) * 4096)
    #define VOFF(gg, cc) (16384 + ((gg) * 2 + (cc)) * 4096)

    const short* Ktile0 = Kb + ((size_t)(b * NH + hd) << 17);
    const short* Vtile0 = Vb + ((size_t)(b * NH + hd) << 17);
    const unsigned* Mrow = mbits + ((size_t)b * LL + qbase + lq) * 64 + g * 32;

    uint2 mreg = *(const uint2*)(Mrow);
    {
        const short* kb_ = Ktile0 + (size_t)(g * 16) * 4096;
        const short* vb_ = Vtile0 + (size_t)(g * 16) * 4096;
        #pragma unroll
        for (int c = 0; c < 2; ++c) {
            __builtin_amdgcn_global_load_lds(
                (const unsigned*)(kb_ + wg * 1024 + c * 512 + lane * 8),
                (unsigned*)&smem[KOFF(g, 0) + wg * 1024 + c * 512], 16, 0, 0);
            __builtin_amdgcn_global_load_lds(
                (const unsigned*)(vb_ + wg * 1024 + c * 512 + lane * 8),
                (unsigned*)&smem[VOFF(g, 0) + wg * 1024 + c * 512], 16, 0, 0);
        }
    }

    // Q fragments, pre-scaled: qf[d16] slot i = SCALE2*Q[q][16d16+8hh+i]
    bf16x8 qf[4];
    {
        const float* qp = Q + ((size_t)b * LL + qbase + lq) * DM + hd * DH + 8 * hh;
        #pragma unroll
        for (int d16 = 0; d16 < 4; ++d16) {
            float4 a = *(const float4*)(qp + 16 * d16);
            float4 c = *(const float4*)(qp + 16 * d16 + 4);
            a.x *= SCALE2; a.y *= SCALE2; a.z *= SCALE2; a.w *= SCALE2;
            c.x *= SCALE2; c.y *= SCALE2; c.z *= SCALE2; c.w *= SCALE2;
            qf[d16] = cvt8(a, c);
        }
    }

    f32x16 o0, o1;
    #pragma unroll
    for (int i = 0; i < 16; ++i) { o0[i] = 0.f; o1[i] = 0.f; }
    float l_own = 0.f;
    float m_shift = 0.f;
    const int sh4 = 4 * hh;

    asm volatile("s_waitcnt vmcnt(0)" ::: "memory");
    __builtin_amdgcn_s_barrier();

    #pragma unroll 2
    for (int t = 0; t < 16; ++t) {
        const int cur = t & 1;
        const uint2 m2 = mreg;
        if (t + 1 < 16) {
            mreg = *(const uint2*)(Mrow + 2 * (t + 1));
            const short* kb_ = Ktile0 + (size_t)(g * 16 + t + 1) * 4096;
            const short* vb_ = Vtile0 + (size_t)(g * 16 + t + 1) * 4096;
            #pragma unroll
            for (int c = 0; c < 2; ++c) {
                __builtin_amdgcn_global_load_lds(
                    (const unsigned*)(kb_ + wg * 1024 + c * 512 + lane * 8),
                    (unsigned*)&smem[KOFF(g, cur ^ 1) + wg * 1024 + c * 512], 16, 0, 0);
                __builtin_amdgcn_global_load_lds(
                    (const unsigned*)(vb_ + wg * 1024 + c * 512 + lane * 8),
                    (unsigned*)&smem[VOFF(g, cur ^ 1) + wg * 1024 + c * 512], 16, 0, 0);
            }
            asm volatile("s_waitcnt vmcnt(5)" ::: "memory");  // drain tile t only
        } else {
            asm volatile("s_waitcnt vmcnt(0)" ::: "memory");
        }
        __builtin_amdgcn_s_barrier();
        __builtin_amdgcn_sched_barrier(0);

        // ---- per key-block: QK -> exp/mask/pack -> (rare) guard -> PV ----
        #pragma unroll
        for (int kb2 = 0; kb2 < 2; ++kb2) {
            f32x16 s;
            #pragma unroll
            for (int i = 0; i < 16; ++i) s[i] = 0.f;
            __builtin_amdgcn_s_setprio(1);
            #pragma unroll
            for (int d16 = 0; d16 < 4; ++d16) {
                bf16x8 kf = *(const bf16x8*)
                    &smem[KOFF(g, cur) + d16 * 1024 + kb2 * 512 + lane * 8];
                s = __builtin_amdgcn_mfma_f32_32x32x16_bf16(kf, qf[d16], s, 0, 0, 0);
            }
            __builtin_amdgcn_s_setprio(0);

            if (__builtin_expect(m_shift != 0.0f, 0)) {   // sticky slow path
                #pragma unroll
                for (int r = 0; r < 16; ++r) s[r] -= m_shift;
            }

            const unsigned nw = (kb2 ? m2.y : m2.x) >> sh4;
            PP pp = packP(s, nw);

            // overflow guard via lsum (no max tree on the fast path)
            if (__builtin_expect(!__all(pp.lsum < 1e30f), 0)) {
                float a0 = fmaxf(fmaxf(s[0], s[1]), fmaxf(s[2], s[3]));
                float a1 = fmaxf(fmaxf(s[4], s[5]), fmaxf(s[6], s[7]));
                float a2 = fmaxf(fmaxf(s[8], s[9]), fmaxf(s[10], s[11]));
                float a3 = fmaxf(fmaxf(s[12], s[13]), fmaxf(s[14], s[15]));
                float mx = fmaxf(fmaxf(a0, a1), fmaxf(a2, a3));
                float tmax = fmaxf(mx, __shfl_xor(mx, 32, 64));
                float shift = tmax - 30.0f;
                m_shift += shift;
                float alpha = exp2_fast(-shift);
                #pragma unroll
                for (int i = 0; i < 16; ++i) { o0[i] *= alpha; o1[i] *= alpha; }
                l_own *= alpha;
                #pragma unroll
                for (int r = 0; r < 16; ++r) s[r] -= shift;
                pp = packP(s, nw);   // recompute with shifted scores
            }
            l_own += pp.lsum;

            __builtin_amdgcn_s_setprio(1);
            {
                const int m0 = kb2 * 2;
                bf16x8 v0 = *(const bf16x8*)&smem[VOFF(g, cur) + m0 * 1024 + lane * 8];
                bf16x8 v1 = *(const bf16x8*)&smem[VOFF(g, cur) + m0 * 1024 + 512 + lane * 8];
                o0 = __builtin_amdgcn_mfma_f32_32x32x16_bf16(v0, pp.pa, o0, 0, 0, 0);
                o1 = __builtin_amdgcn_mfma_f32_32x32x16_bf16(v1, pp.pa, o1, 0, 0, 0);
                bf16x8 v2 = *(const bf16x8*)&smem[VOFF(g, cur) + (m0 + 1) * 1024 + lane * 8];
                bf16x8 v3 = *(const bf16x8*)&smem[VOFF(g, cur) + (m0 + 1) * 1024 + 512 + lane * 8];
                o0 = __builtin_amdgcn_mfma_f32_32x32x16_bf16(v2, pp.pb, o0, 0, 0, 0);
                o1 = __builtin_amdgcn_mfma_f32_32x32x16_bf16(v3, pp.pb, o1, 0, 0, 0);
            }
            __builtin_amdgcn_s_setprio(0);
        }

        __builtin_amdgcn_sched_barrier(0);
        __builtin_amdgcn_s_barrier();
    }

    // ---- kv-split combine via LDS (group1 -> group0), then store ----
    float* cb = (float*)smem;
    const int cbase = (wg * 64 + lane) * 34;
    if (g == 1) {
        #pragma unroll
        for (int i = 0; i < 16; ++i) { cb[cbase + i] = o0[i]; cb[cbase + 16 + i] = o1[i]; }
        cb[cbase + 32] = l_own;
        cb[cbase + 33] = m_shift;
    }
    __syncthreads();
    if (g == 0) {
        float msB = cb[cbase + 33];
        float lB = cb[cbase + 32];
        float M = fmaxf(m_shift, msB);
        float aA = exp2_fast(m_shift - M);
        float aB = exp2_fast(msB - M);
        float lc = l_own * aA + lB * aB;
        lc += __shfl_xor(lc, 32, 64);
        float inv = __builtin_amdgcn_rcpf(lc);
        #pragma unroll
        for (int i = 0; i < 16; ++i) {
            o0[i] = (o0[i] * aA + cb[cbase + i] * aB) * inv;
            o1[i] = (o1[i] * aA + cb[cbase + 16 + i] * aB) * inv;
        }
        float* fout = out + ((size_t)b * LL + qbase + lq) * DM + hd * DH + 4 * hh;
        #pragma unroll
        for (int rg = 0; rg < 4; ++rg) {
            float4 v0, v1;
            v0.x = o0[4 * rg + 0]; v0.y = o0[4 * rg + 1];
            v0.z = o0[4 * rg + 2]; v0.w = o0[4 * rg + 3];
            v1.x = o1[4 * rg + 0]; v1.y = o1[4 * rg + 1];
            v1.z = o1[4 * rg + 2]; v1.w = o1[4 * rg + 3];
            *(float4*)(fout + 8 * rg) = v0;
            *(float4*)(fout + 32 + 8 * rg) = v1;
        }
    }
    #undef KOFF
    #undef VOFF
}

extern "C" void kernel_launch(void* const* d_in, const int* in_sizes, int n_in,
                              void* d_out, int out_size, void* d_ws, size_t ws_size,
                              hipStream_t stream) {
    const float* Q = (const float*)d_in[0];
    const float* K = (const float*)d_in[1];
    const float* V = (const float*)d_in[2];
    const void* mask = d_in[3];
    float* out = (float*)d_out;

    const size_t MASK_B = (size_t)2 * LL * 64 * 4;        // 1 MB
    const size_t K_B = (size_t)2 * NH * 32 * 4096 * 2;    // 8 MB
    unsigned* bits = (unsigned*)d_ws;
    short* Kb = (short*)((char*)d_ws + MASK_B);
    short* Vb = (short*)((char*)d_ws + MASK_B + K_B);

    pack_mask<<<dim3(2 * LL * 64 / 256), dim3(256), 0, stream>>>(mask, bits);
    prep_kv<<<dim3(32, NH, 2), dim3(512), 0, stream>>>(K, V, Kb, Vb);
    mha_fwd6<<<dim3(512), dim3(512), 0, stream>>>(Q, Kb, Vb, bits, out);
}

// Round 19
// 75.407 us; speedup vs baseline: 3.5483x; 1.0205x over previous
//
#include <hip/hip_runtime.h>
#include <hip/hip_bf16.h>

#define NH 16
#define DH 64
#define LL 2048
#define DM 1024
#define SCALE2 0.1803368801111204f   /* 0.125 * log2(e) */

typedef __attribute__((ext_vector_type(4))) float f32x4;
typedef __attribute__((ext_vector_type(16))) float f32x16;
typedef __attribute__((ext_vector_type(8))) short bf16x8;

__device__ __forceinline__ unsigned pk2(float lo, float hi) {
    __hip_bfloat162 h = __float22bfloat162_rn(make_float2(lo, hi));
    union { __hip_bfloat162 h; unsigned u; } c; c.h = h; return c.u;
}
__device__ __forceinline__ bf16x8 cvt8(float4 a, float4 b) {
    union { bf16x8 v; unsigned u[4]; } r;
    r.u[0] = pk2(a.x, a.y); r.u[1] = pk2(a.z, a.w);
    r.u[2] = pk2(b.x, b.y); r.u[3] = pk2(b.z, b.w);
    return r.v;
}
__device__ __forceinline__ float exp2_fast(float x) {
    float y;
    asm("v_exp_f32 %0, %1" : "=v"(y) : "v"(x));
    return y;
}
__device__ __forceinline__ float keepf(float p, unsigned nw, int idx) {
    int k = (int)(nw << (31 - idx)) >> 31;
    unsigned pu = __builtin_bit_cast(unsigned, p) & (unsigned)k;
    return __builtin_bit_cast(float, pu);
}

// exp + mask + pack for one 32-key score block (bit map: keys 8*(r>>2)+(r&3))
struct PP { bf16x8 pa, pb; float lsum; };
__device__ __forceinline__ PP packP(const f32x16& s, unsigned nw) {
    PP r;
    union { bf16x8 v; unsigned u[4]; } pa, pb;
    float p0 = keepf(exp2_fast(s[0]), nw, 0);
    float p1 = keepf(exp2_fast(s[1]), nw, 1);
    float p2 = keepf(exp2_fast(s[2]), nw, 2);
    float p3 = keepf(exp2_fast(s[3]), nw, 3);
    float p4 = keepf(exp2_fast(s[4]), nw, 8);
    float p5 = keepf(exp2_fast(s[5]), nw, 9);
    float p6 = keepf(exp2_fast(s[6]), nw, 10);
    float p7 = keepf(exp2_fast(s[7]), nw, 11);
    pa.u[0] = pk2(p0, p1); pa.u[1] = pk2(p2, p3);
    pa.u[2] = pk2(p4, p5); pa.u[3] = pk2(p6, p7);
    float lsum = ((p0 + p1) + (p2 + p3)) + ((p4 + p5) + (p6 + p7));
    float q0 = keepf(exp2_fast(s[8]), nw, 16);
    float q1 = keepf(exp2_fast(s[9]), nw, 17);
    float q2 = keepf(exp2_fast(s[10]), nw, 18);
    float q3 = keepf(exp2_fast(s[11]), nw, 19);
    float q4 = keepf(exp2_fast(s[12]), nw, 24);
    float q5 = keepf(exp2_fast(s[13]), nw, 25);
    float q6 = keepf(exp2_fast(s[14]), nw, 26);
    float q7 = keepf(exp2_fast(s[15]), nw, 27);
    pb.u[0] = pk2(q0, q1); pb.u[1] = pk2(q2, q3);
    pb.u[2] = pk2(q4, q5); pb.u[3] = pk2(q6, q7);
    lsum += ((q0 + q1) + (q2 + q3)) + ((q4 + q5) + (q6 + q7));
    r.pa = pa.v; r.pb = pb.v; r.lsum = lsum;
    return r;
}

// ---- fused prep: blocks 0..1023 = K/V bf16 convert; 1024..1535 = mask pack
// (mask needs 2*LL*64 = 262144 words = 512 blocks x 512 thr)
__global__ __launch_bounds__(512) void prep_fused(const float* __restrict__ K,
                                                  const float* __restrict__ V,
                                                  const void* __restrict__ mask,
                                                  short* __restrict__ Kb,
                                                  short* __restrict__ Vb,
                                                  unsigned* __restrict__ bits)
{
    const int bid = blockIdx.x;
    const int tid = threadIdx.x;
    if (bid < 1024) {          // ---- K/V convert ----
        const int kt = bid & 31;
        const int h = (bid >> 5) & 15;
        const int b = bid >> 9;
        if (tid < 256) {
            const int key = tid >> 2;
            const int d16 = tid & 3;
            const float* src = K + ((size_t)b * LL + kt * 64 + key) * DM + h * DH + d16 * 16;
            float4 f0 = *(const float4*)(src);
            float4 f1 = *(const float4*)(src + 4);
            float4 f2 = *(const float4*)(src + 8);
            float4 f3 = *(const float4*)(src + 12);
            short* dst = Kb + (((size_t)(b * NH + h) * 32 + kt) << 12);
            const int base = d16 * 1024 + (key >> 5) * 512 + (key & 31) * 8;
            *(bf16x8*)&dst[base] = cvt8(f0, f1);           // hh=0
            *(bf16x8*)&dst[base + 256] = cvt8(f2, f3);     // hh=1
        } else {
            const int vt = tid - 256;
            const int kp = vt & 31;               // keys 2kp, 2kp+1
            const int dv8 = vt >> 5;
            const float* s0 = V + ((size_t)b * LL + kt * 64 + 2 * kp) * DM + h * DH + dv8 * 8;
            float4 a0 = *(const float4*)(s0);
            float4 a1 = *(const float4*)(s0 + 4);
            float4 b0 = *(const float4*)(s0 + DM);
            float4 b1 = *(const float4*)(s0 + DM + 4);
            float av[8] = {a0.x, a0.y, a0.z, a0.w, a1.x, a1.y, a1.z, a1.w};
            float bv[8] = {b0.x, b0.y, b0.z, b0.w, b1.x, b1.y, b1.z, b1.w};
            short* dst = Vb + (((size_t)(b * NH + h) * 32 + kt) << 12);
            const int key0 = 2 * kp;
            const int m = key0 >> 4;
            const int w16 = key0 & 15;
            const int hh = (w16 >> 2) & 1;
            const int i0 = (w16 & 3) + 4 * (w16 >> 3);
            #pragma unroll
            for (int j = 0; j < 8; ++j) {
                int dv = dv8 * 8 + j;
                int off = m * 1024 + (dv >> 5) * 512 + hh * 256 + (dv & 31) * 8 + i0;
                *(unsigned*)&dst[off] = pk2(av[j], bv[j]);
            }
        }
    } else {                   // ---- mask pack: 512 blocks x 512 thr ----
        const int lane = tid & 63;
        const int* mw = (const int*)mask;
        unsigned long long bad = __ballot((unsigned)mw[lane] > 1u);
        const bool is_int = (bad == 0ULL);

        const int wid = (bid - 1024) * 512 + tid;   // 0 .. 2*LL*64-1
        const int kw = wid & 63;
        const int q64 = wid >> 6;
        unsigned m = 0;
        if (is_int) {
            const int* p = (const int*)mask + (size_t)q64 * LL + kw * 32;
            #pragma unroll
            for (int j = 0; j < 32; j += 4) {
                int4 v = *(const int4*)(p + j);
                m |= (v.x ? 1u : 0u) << j;
                m |= (v.y ? 1u : 0u) << (j + 1);
                m |= (v.z ? 1u : 0u) << (j + 2);
                m |= (v.w ? 1u : 0u) << (j + 3);
            }
        } else {
            const unsigned* p = (const unsigned*)((const unsigned char*)mask
                                                  + (size_t)q64 * LL + kw * 32);
            #pragma unroll
            for (int j = 0; j < 8; ++j) {
                unsigned v = p[j];
                m |= (v & 1u) << (4 * j);
                m |= ((v >> 8) & 1u) << (4 * j + 1);
                m |= ((v >> 16) & 1u) << (4 * j + 2);
                m |= ((v >> 24) & 1u) << (4 * j + 3);
            }
        }
        bits[wid] = ~m;   // 1 = keep
    }
}

// ---- main (R17, unchanged): 512 blocks x 512 thr,
//      2 kv-groups x 4 waves x 32q, 64-key tiles, counted vmcnt(5) ----
__global__ __launch_bounds__(512, 4) void mha_fwd6(
    const float* __restrict__ Q, const short* __restrict__ Kb,
    const short* __restrict__ Vb, const unsigned* __restrict__ mbits,
    float* __restrict__ out)
{
    const int bid = blockIdx.x;
    const int xcd = bid & 7;
    const int j = bid >> 3;
    const int pair = xcd * 4 + (j >> 4);
    const int qblk = j & 15;
    const int hd = pair & 15;
    const int b = pair >> 4;

    const int tid = threadIdx.x;
    const int w = tid >> 6;
    const int g = w >> 2;                 // kv-group 0/1
    const int wg = w & 3;                 // wave in group
    const int lane = tid & 63;
    const int lq = lane & 31;
    const int hh = lane >> 5;
    const int qbase = qblk * 128 + wg * 32;

    __shared__ short smem[32768];         // 64 KB
    #define KOFF(gg, cc) (((gg) * 2 + (cc)) * 4096)
    #define VOFF(gg, cc) (16384 + ((gg) * 2 + (cc)) * 4096)

    const short* Ktile0 = Kb + ((size_t)(b * NH + hd) << 17);
    const short* Vtile0 = Vb + ((size_t)(b * NH + hd) << 17);
    const unsigned* Mrow = mbits + ((size_t)b * LL + qbase + lq) * 64 + g * 32;

    uint2 mreg = *(const uint2*)(Mrow);
    {
        const short* kb_ = Ktile0 + (size_t)(g * 16) * 4096;
        const short* vb_ = Vtile0 + (size_t)(g * 16) * 4096;
        #pragma unroll
        for (int c = 0; c < 2; ++c) {
            __builtin_amdgcn_global_load_lds(
                (const unsigned*)(kb_ + wg * 1024 + c * 512 + lane * 8),
                (unsigned*)&smem[KOFF(g, 0) + wg * 1024 + c * 512], 16, 0, 0);
            __builtin_amdgcn_global_load_lds(
                (const unsigned*)(vb_ + wg * 1024 + c * 512 + lane * 8),
                (unsigned*)&smem[VOFF(g, 0) + wg * 1024 + c * 512], 16, 0, 0);
        }
    }

    // Q fragments, pre-scaled: qf[d16] slot i = SCALE2*Q[q][16d16+8hh+i]
    bf16x8 qf[4];
    {
        const float* qp = Q + ((size_t)b * LL + qbase + lq) * DM + hd * DH + 8 * hh;
        #pragma unroll
        for (int d16 = 0; d16 < 4; ++d16) {
            float4 a = *(const float4*)(qp + 16 * d16);
            float4 c = *(const float4*)(qp + 16 * d16 + 4);
            a.x *= SCALE2; a.y *= SCALE2; a.z *= SCALE2; a.w *= SCALE2;
            c.x *= SCALE2; c.y *= SCALE2; c.z *= SCALE2; c.w *= SCALE2;
            qf[d16] = cvt8(a, c);
        }
    }

    f32x16 o0, o1;
    #pragma unroll
    for (int i = 0; i < 16; ++i) { o0[i] = 0.f; o1[i] = 0.f; }
    float l_own = 0.f;
    float m_shift = 0.f;
    const int sh4 = 4 * hh;

    asm volatile("s_waitcnt vmcnt(0)" ::: "memory");
    __builtin_amdgcn_s_barrier();

    #pragma unroll 2
    for (int t = 0; t < 16; ++t) {
        const int cur = t & 1;
        const uint2 m2 = mreg;
        if (t + 1 < 16) {
            mreg = *(const uint2*)(Mrow + 2 * (t + 1));
            const short* kb_ = Ktile0 + (size_t)(g * 16 + t + 1) * 4096;
            const short* vb_ = Vtile0 + (size_t)(g * 16 + t + 1) * 4096;
            #pragma unroll
            for (int c = 0; c < 2; ++c) {
                __builtin_amdgcn_global_load_lds(
                    (const unsigned*)(kb_ + wg * 1024 + c * 512 + lane * 8),
                    (unsigned*)&smem[KOFF(g, cur ^ 1) + wg * 1024 + c * 512], 16, 0, 0);
                __builtin_amdgcn_global_load_lds(
                    (const unsigned*)(vb_ + wg * 1024 + c * 512 + lane * 8),
                    (unsigned*)&smem[VOFF(g, cur ^ 1) + wg * 1024 + c * 512], 16, 0, 0);
            }
            asm volatile("s_waitcnt vmcnt(5)" ::: "memory");  // drain tile t only
        } else {
            asm volatile("s_waitcnt vmcnt(0)" ::: "memory");
        }
        __builtin_amdgcn_s_barrier();
        __builtin_amdgcn_sched_barrier(0);

        // ---- per key-block: QK -> exp/mask/pack -> (rare) guard -> PV ----
        #pragma unroll
        for (int kb2 = 0; kb2 < 2; ++kb2) {
            f32x16 s;
            #pragma unroll
            for (int i = 0; i < 16; ++i) s[i] = 0.f;
            __builtin_amdgcn_s_setprio(1);
            #pragma unroll
            for (int d16 = 0; d16 < 4; ++d16) {
                bf16x8 kf = *(const bf16x8*)
                    &smem[KOFF(g, cur) + d16 * 1024 + kb2 * 512 + lane * 8];
                s = __builtin_amdgcn_mfma_f32_32x32x16_bf16(kf, qf[d16], s, 0, 0, 0);
            }
            __builtin_amdgcn_s_setprio(0);

            if (__builtin_expect(m_shift != 0.0f, 0)) {   // sticky slow path
                #pragma unroll
                for (int r = 0; r < 16; ++r) s[r] -= m_shift;
            }

            const unsigned nw = (kb2 ? m2.y : m2.x) >> sh4;
            PP pp = packP(s, nw);

            // overflow guard via lsum (no max tree on the fast path)
            if (__builtin_expect(!__all(pp.lsum < 1e30f), 0)) {
                float a0 = fmaxf(fmaxf(s[0], s[1]), fmaxf(s[2], s[3]));
                float a1 = fmaxf(fmaxf(s[4], s[5]), fmaxf(s[6], s[7]));
                float a2 = fmaxf(fmaxf(s[8], s[9]), fmaxf(s[10], s[11]));
                float a3 = fmaxf(fmaxf(s[12], s[13]), fmaxf(s[14], s[15]));
                float mx = fmaxf(fmaxf(a0, a1), fmaxf(a2, a3));
                float tmax = fmaxf(mx, __shfl_xor(mx, 32, 64));
                float shift = tmax - 30.0f;
                m_shift += shift;
                float alpha = exp2_fast(-shift);
                #pragma unroll
                for (int i = 0; i < 16; ++i) { o0[i] *= alpha; o1[i] *= alpha; }
                l_own *= alpha;
                #pragma unroll
                for (int r = 0; r < 16; ++r) s[r] -= shift;
                pp = packP(s, nw);   // recompute with shifted scores
            }
            l_own += pp.lsum;

            __builtin_amdgcn_s_setprio(1);
            {
                const int m0 = kb2 * 2;
                bf16x8 v0 = *(const bf16x8*)&smem[VOFF(g, cur) + m0 * 1024 + lane * 8];
                bf16x8 v1 = *(const bf16x8*)&smem[VOFF(g, cur) + m0 * 1024 + 512 + lane * 8];
                o0 = __builtin_amdgcn_mfma_f32_32x32x16_bf16(v0, pp.pa, o0, 0, 0, 0);
                o1 = __builtin_amdgcn_mfma_f32_32x32x16_bf16(v1, pp.pa, o1, 0, 0, 0);
                bf16x8 v2 = *(const bf16x8*)&smem[VOFF(g, cur) + (m0 + 1) * 1024 + lane * 8];
                bf16x8 v3 = *(const bf16x8*)&smem[VOFF(g, cur) + (m0 + 1) * 1024 + 512 + lane * 8];
                o0 = __builtin_amdgcn_mfma_f32_32x32x16_bf16(v2, pp.pb, o0, 0, 0, 0);
                o1 = __builtin_amdgcn_mfma_f32_32x32x16_bf16(v3, pp.pb, o1, 0, 0, 0);
            }
            __builtin_amdgcn_s_setprio(0);
        }

        __builtin_amdgcn_sched_barrier(0);
        __builtin_amdgcn_s_barrier();
    }

    // ---- kv-split combine via LDS (group1 -> group0), then store ----
    float* cb = (float*)smem;
    const int cbase = (wg * 64 + lane) * 34;
    if (g == 1) {
        #pragma unroll
        for (int i = 0; i < 16; ++i) { cb[cbase + i] = o0[i]; cb[cbase + 16 + i] = o1[i]; }
        cb[cbase + 32] = l_own;
        cb[cbase + 33] = m_shift;
    }
    __syncthreads();
    if (g == 0) {
        float msB = cb[cbase + 33];
        float lB = cb[cbase + 32];
        float M = fmaxf(m_shift, msB);
        float aA = exp2_fast(m_shift - M);
        float aB = exp2_fast(msB - M);
        float lc = l_own * aA + lB * aB;
        lc += __shfl_xor(lc, 32, 64);
        float inv = __builtin_amdgcn_rcpf(lc);
        #pragma unroll
        for (int i = 0; i < 16; ++i) {
            o0[i] = (o0[i] * aA + cb[cbase + i] * aB) * inv;
            o1[i] = (o1[i] * aA + cb[cbase + 16 + i] * aB) * inv;
        }
        float* fout = out + ((size_t)b * LL + qbase + lq) * DM + hd * DH + 4 * hh;
        #pragma unroll
        for (int rg = 0; rg < 4; ++rg) {
            float4 v0, v1;
            v0.x = o0[4 * rg + 0]; v0.y = o0[4 * rg + 1];
            v0.z = o0[4 * rg + 2]; v0.w = o0[4 * rg + 3];
            v1.x = o1[4 * rg + 0]; v1.y = o1[4 * rg + 1];
            v1.z = o1[4 * rg + 2]; v1.w = o1[4 * rg + 3];
            *(float4*)(fout + 8 * rg) = v0;
            *(float4*)(fout + 32 + 8 * rg) = v1;
        }
    }
    #undef KOFF
    #undef VOFF
}

extern "C" void kernel_launch(void* const* d_in, const int* in_sizes, int n_in,
                              void* d_out, int out_size, void* d_ws, size_t ws_size,
                              hipStream_t stream) {
    const float* Q = (const float*)d_in[0];
    const float* K = (const float*)d_in[1];
    const float* V = (const float*)d_in[2];
    const void* mask = d_in[3];
    float* out = (float*)d_out;

    const size_t MASK_B = (size_t)2 * LL * 64 * 4;        // 1 MB
    const size_t K_B = (size_t)2 * NH * 32 * 4096 * 2;    // 8 MB
    unsigned* bits = (unsigned*)d_ws;
    short* Kb = (short*)((char*)d_ws + MASK_B);
    short* Vb = (short*)((char*)d_ws + MASK_B + K_B);

    prep_fused<<<dim3(1536), dim3(512), 0, stream>>>(K, V, mask, Kb, Vb, bits);
    mha_fwd6<<<dim3(512), dim3(512), 0, stream>>>(Q, Kb, Vb, bits, out);
}